// Round 9
// baseline (318.805 us; speedup 1.0000x reference)
//
#include <hip/hip_runtime.h>
#include <math.h>

// TriOut: z[L,L,Z] -> LN -> gated proj to C -> einsum('ilc,jlc->ijc') -> LN(C)
//         -> proj back to Z -> * sigmoid(zn@g_w+g_b)
// L=768, Z=128, C=32.  Output fp32 [L,L,Z].
//
// ws layout (all disjoint):
//   a_t   : bf16 [C][L*L]        ( 37,748,736 B) @ 0          a, c-major
//   znfrag: bf16 [LL/16][4][64][8](150,994,944 B) @ 37748736  LN(z) in A-frag order
//   obuf16: bf16 [C][L*L]        ( 37,748,736 B) @ 188743680  einsum result, c-major
//   afrag : bf16 [16][64][8]     ( 16,384 B)     @ 226492416  a/ag weights, frag order
//   gfrag : bf16 [32][64][8]     ( 32,768 B)     @ 226508800  g_w frag order
//   ofrag : bf16 [ 8][64][8]     (  8,192 B)     @ 226541568  o_w frag order

#define LDIM 768
#define LL   (768 * 768)
#define ZD   128
#define CD   32

typedef __bf16 bf16x8 __attribute__((ext_vector_type(8)));
typedef float  f32x4  __attribute__((ext_vector_type(4)));

__device__ __forceinline__ ushort f2bf(float f) {
    __bf16 h = (__bf16)f;                      // RNE convert
    return __builtin_bit_cast(ushort, h);
}
__device__ __forceinline__ float bf2f(ushort u) {
    return __builtin_bit_cast(float, ((unsigned)u) << 16);
}
// fast sigmoid: v_exp_f32 + v_rcp_f32 (~1 ulp fp32 -- far below bf16 rounding)
__device__ __forceinline__ float sigm(float x) {
    return __builtin_amdgcn_rcpf(1.0f + __expf(-x));
}

// ---------------------------------------------------------------------------
// k0: pack weights into MFMA B-fragment order (frag f, lane l=(fr,hi)):
//   afrag[f=t*4+kk][l] = W_t[(t&1)*16+fr][kk*32+hi*8+j], t: 0,1=a_w 2,3=ag_w
//   gfrag[f=n*4+kk][l] = g_w[n*16+fr][kk*32+hi*8+j]
//   ofrag[f=n     ][l] = o_w[n*16+fr][hi*8+j]            (K=32, single step)
// ---------------------------------------------------------------------------
__global__ __launch_bounds__(256) void k0_frags(
    const float* __restrict__ aw, const float* __restrict__ agw,
    const float* __restrict__ gw, const float* __restrict__ ow,
    ushort* __restrict__ afrag, ushort* __restrict__ gfrag,
    ushort* __restrict__ ofrag)
{
    const int idx = blockIdx.x * 256 + threadIdx.x;   // 3584 total
    if (idx >= 3584) return;
    const int lane = idx & 63;
    const int fr = lane & 15, hi = lane >> 4;
    union { ushort us[8]; uint4 q; } pk;
    if (idx < 1024) {                 // afrag
        const int f = idx >> 6, t = f >> 2, kk = f & 3;
        const float* src = ((t < 2) ? aw : agw) + ((t & 1) * 16 + fr) * ZD + kk * 32 + hi * 8;
        #pragma unroll
        for (int j = 0; j < 8; ++j) pk.us[j] = f2bf(src[j]);
        *(uint4*)&afrag[(size_t)f * 512 + lane * 8] = pk.q;
    } else if (idx < 3072) {          // gfrag
        const int f = (idx - 1024) >> 6, n = f >> 2, kk = f & 3;
        const float* src = gw + (n * 16 + fr) * ZD + kk * 32 + hi * 8;
        #pragma unroll
        for (int j = 0; j < 8; ++j) pk.us[j] = f2bf(src[j]);
        *(uint4*)&gfrag[(size_t)f * 512 + lane * 8] = pk.q;
    } else {                          // ofrag
        const int n = (idx - 3072) >> 6;
        const float* src = ow + (n * 16 + fr) * CD + hi * 8;
        #pragma unroll
        for (int j = 0; j < 8; ++j) pk.us[j] = f2bf(src[j]);
        *(uint4*)&ofrag[(size_t)n * 512 + lane * 8] = pk.q;
    }
}

// ---------------------------------------------------------------------------
// k1 v5: BARRIER-FREE.  2304 blocks x 4 chunks x 64 rows; wave w owns rows
// w*16..+15.  LN threads hold the 4 A-frag units of their row-segment in regs
// and store them STRAIGHT to global znfrag (dense 64B-line coalescing) -- no
// LDS round-trip for zn.  znw LDS only feeds the wave's own a/ag MFMA A-frags.
// ---------------------------------------------------------------------------
__global__ __launch_bounds__(256) void k1_ln_proj(
    const float* __restrict__ z, const float* __restrict__ nw, const float* __restrict__ nb,
    const ushort* __restrict__ afrag,
    const float* __restrict__ ab, const float* __restrict__ agb,
    ushort* __restrict__ a_t, ushort* __restrict__ znfrag)
{
    __shared__ ushort znw[4][16][136];

    const int tid = threadIdx.x;
    const int lane = tid & 63, wave = tid >> 6;
    const int fr = lane & 15, hi = lane >> 4;

    // B-frags: 4 tiles (a0,a1,ag0,ag1) x 4 k, held in 64 VGPR
    bf16x8 bfr[4][4];
    {
        const ushort* wl = afrag + (size_t)lane * 8;
        #pragma unroll
        for (int t = 0; t < 4; ++t)
            #pragma unroll
            for (int kk = 0; kk < 4; ++kk)
                bfr[t][kk] = *(const bf16x8*)(wl + (size_t)(t * 4 + kk) * 512);
    }
    const float ab0 = ab[fr], ab1 = ab[16 + fr];
    const float agb0 = agb[fr], agb1 = agb[16 + fr];

    const size_t blockrow = (size_t)blockIdx.x * 256;
    const int lr = lane >> 2, seg = lane & 3;     // LN: 4 lanes/row, 16 rows/wave

    float4 zreg[8];
    {
        const float4* zp = (const float4*)(z + (blockrow + wave * 16 + lr) * ZD + seg * 32);
        #pragma unroll
        for (int q = 0; q < 8; ++q) zreg[q] = zp[q];
    }

    for (int c = 0; c < 4; ++c) {
        const size_t rowc = blockrow + c * 64 + wave * 16;
        const size_t tile = rowc >> 4;

        // ---- LN from prefetched regs -> pk units ----
        union { ushort u[32]; uint4 q4[4]; } pk;
        {
            float v[32];
            #pragma unroll
            for (int q = 0; q < 8; ++q) {
                v[q * 4 + 0] = zreg[q].x; v[q * 4 + 1] = zreg[q].y;
                v[q * 4 + 2] = zreg[q].z; v[q * 4 + 3] = zreg[q].w;
            }
            float s = 0.f, ss = 0.f;
            #pragma unroll
            for (int e = 0; e < 32; ++e) { s += v[e]; ss += v[e] * v[e]; }
            s += __shfl_xor(s, 1); ss += __shfl_xor(ss, 1);
            s += __shfl_xor(s, 2); ss += __shfl_xor(ss, 2);
            const float mu  = s * (1.f / 128.f);
            const float var = ss * (1.f / 128.f) - mu * mu;
            const float rs  = rsqrtf(var + 1e-5f);
            #pragma unroll
            for (int e = 0; e < 32; ++e) {
                const int k = seg * 32 + e;
                pk.u[e] = f2bf((v[e] - mu) * rs * nw[k] + nb[k]);
            }
        }
        // znw for own A-frags
        #pragma unroll
        for (int q = 0; q < 4; ++q)
            *(uint4*)&znw[wave][lr][seg * 32 + q * 8] = pk.q4[q];
        // direct frag-order global stores (unit (fr=lr, kk=seg, hi=h2))
        #pragma unroll
        for (int h2 = 0; h2 < 4; ++h2)
            *(uint4*)&znfrag[((tile * 4 + seg) * 64 + lr + 16 * h2) * 8] = pk.q4[h2];

        // ---- prefetch next chunk's z ----
        if (c < 3) {
            const float4* zp = (const float4*)(z + (rowc + 64 + lr) * ZD + seg * 32);
            #pragma unroll
            for (int q = 0; q < 8; ++q) zreg[q] = zp[q];
        }

        // ---- MFMA: 4 tiles x 4 k for this wave's 16 rows ----
        bf16x8 af[4];
        #pragma unroll
        for (int kk = 0; kk < 4; ++kk)
            af[kk] = *(const bf16x8*)&znw[wave][fr][kk * 32 + hi * 8];

        f32x4 acc[4];
        #pragma unroll
        for (int t = 0; t < 4; ++t) acc[t] = (f32x4){0.f, 0.f, 0.f, 0.f};
        #pragma unroll
        for (int kk = 0; kk < 4; ++kk)
            #pragma unroll
            for (int t = 0; t < 4; ++t)
                acc[t] = __builtin_amdgcn_mfma_f32_16x16x32_bf16(af[kk], bfr[t][kk], acc[t], 0, 0, 0);

        // ---- epilogue: a = (a_lin+ab)*sigm(ag_lin+agb) -> a_t c-major ----
        {
            union { ushort u[4]; uint2 d; } pw;
            #pragma unroll
            for (int q = 0; q < 4; ++q)
                pw.u[q] = f2bf((acc[0][q] + ab0) * sigm(acc[2][q] + agb0));
            *(uint2*)&a_t[(size_t)fr * LL + rowc + hi * 4] = pw.d;
            #pragma unroll
            for (int q = 0; q < 4; ++q)
                pw.u[q] = f2bf((acc[1][q] + ab1) * sigm(acc[3][q] + agb1));
            *(uint2*)&a_t[(size_t)(16 + fr) * LL + rowc + hi * 4] = pw.d;
        }
    }
}

// ---------------------------------------------------------------------------
// k2: 32 batched SYMMETRIC GEMMs  O_c = M_c * M_c^T, upper-triangular tiles
// only (78 pairs), mirror-write for off-diagonal.  Output bf16 obuf16.
// Staging via global_load_lds (linear dest = tid*16B).
// ---------------------------------------------------------------------------
__global__ __launch_bounds__(256) void k2_einsum(
    const ushort* __restrict__ a_t, ushort* __restrict__ obuf16)
{
    __shared__ ushort As[2][64][32];
    __shared__ ushort Bs[2][64][32];

    const int tid = threadIdx.x;
    const int c = blockIdx.y;
    int p = blockIdx.x, bi = 0;
    while (p >= 12 - bi) { p -= 12 - bi; ++bi; }
    const int bj = bi + p;
    const int i0 = bi * 64, j0 = bj * 64;
    const ushort* base = a_t + (size_t)c * LL;

    const int srow = tid >> 2, scol = (tid & 3) * 8;
    const ushort* gA = base + (size_t)(i0 + srow) * LDIM + scol;
    const ushort* gB = base + (size_t)(j0 + srow) * LDIM + scol;

    const int wave = tid >> 6, lane = tid & 63;
    const int wi = (wave >> 1) * 32, wj = (wave & 1) * 32;
    const int fr = lane & 15, k8 = (lane >> 4) * 8;

    f32x4 acc[2][2];
    #pragma unroll
    for (int m = 0; m < 2; ++m)
        #pragma unroll
        for (int n = 0; n < 2; ++n)
            acc[m][n] = (f32x4){0.f, 0.f, 0.f, 0.f};

    auto stage = [&](int b, int kc) {
        __builtin_amdgcn_global_load_lds(
            (const uint*)(gA + kc * 32), (uint*)&As[b][srow][scol], 16, 0, 0);
        __builtin_amdgcn_global_load_lds(
            (const uint*)(gB + kc * 32), (uint*)&Bs[b][srow][scol], 16, 0, 0);
    };

    stage(0, 0);
    __syncthreads();
    for (int kc = 0; kc < 24; ++kc) {
        const int cur = kc & 1;
        if (kc + 1 < 24) stage(cur ^ 1, kc + 1);

        bf16x8 av[2], bv[2];
        #pragma unroll
        for (int m = 0; m < 2; ++m)
            av[m] = *(const bf16x8*)&As[cur][wi + m * 16 + fr][k8];
        #pragma unroll
        for (int n = 0; n < 2; ++n)
            bv[n] = *(const bf16x8*)&Bs[cur][wj + n * 16 + fr][k8];

        #pragma unroll
        for (int m = 0; m < 2; ++m)
            #pragma unroll
            for (int n = 0; n < 2; ++n)
                acc[m][n] = __builtin_amdgcn_mfma_f32_16x16x32_bf16(
                    av[m], bv[n], acc[m][n], 0, 0, 0);
        __syncthreads();
    }

    ushort* ob = obuf16 + (size_t)c * LL;
    #pragma unroll
    for (int m = 0; m < 2; ++m)
        #pragma unroll
        for (int n = 0; n < 2; ++n) {
            #pragma unroll
            for (int q = 0; q < 4; ++q) {
                const int row = i0 + wi + m * 16 + (lane >> 4) * 4 + q;
                const int col = j0 + wj + n * 16 + fr;
                ob[(size_t)row * LDIM + col] = f2bf(acc[m][n][q]);
            }
            if (bi != bj) {
                const int mrow = j0 + wj + n * 16 + fr;
                const int mcol = i0 + wi + m * 16 + (lane >> 4) * 4;
                union { ushort u[4]; uint2 d; } pk;
                #pragma unroll
                for (int q = 0; q < 4; ++q) pk.u[q] = f2bf(acc[m][n][q]);
                *(uint2*)&ob[(size_t)mrow * LDIM + mcol] = pk.d;
            }
        }
}

// ---------------------------------------------------------------------------
// k3 v3: per 64 rows.  LDS = Ol (gather) + Res (transpose) = 26.1 KB.
//   - g-proj A-frags read coalesced from znfrag (issued before the barrier).
//   - LN(C) -> An fragment delivered via 4 cross-lane __shfl (no LDS).
//   - two 64-channel halves computed sequentially (half the acc VGPRs).
//   ONE barrier.
// ---------------------------------------------------------------------------
__global__ __launch_bounds__(256) void k3_out(
    const ushort* __restrict__ obuf16, const ushort* __restrict__ znfrag,
    const float* __restrict__ onw, const float* __restrict__ onb,
    const ushort* __restrict__ gfrag, const ushort* __restrict__ ofrag,
    const float* __restrict__ obias, const float* __restrict__ gb,
    float* __restrict__ out)
{
    __shared__ float Ol[64][33];
    __shared__ float Res[4][16][69];

    const int tid = threadIdx.x;
    const int lane = tid & 63, wave = tid >> 6;
    const int fr = lane & 15, hi = lane >> 4;
    const size_t rowbase = (size_t)blockIdx.x * 64;
    const int wrow = wave * 16;
    const size_t tile = (rowbase + wrow) >> 4;

    // ---- g-proj A-frags from znfrag (coalesced 1KB bursts; issued early) ----
    bf16x8 afg[4];
    #pragma unroll
    for (int kk = 0; kk < 4; ++kk)
        afg[kk] = *(const bf16x8*)&znfrag[((tile * 4 + kk) * 64 + lane) * 8];

    // ---- gather obuf16 (c-major, bf16): wave handles 8 channels ----
    #pragma unroll
    for (int cc = 0; cc < 4; ++cc) {
        const int ch = wave * 8 + cc * 2 + (lane >> 5);
        const int r2 = (lane & 31) * 2;
        const uint u = *(const uint*)&obuf16[(size_t)ch * LL + rowbase + r2];
        Ol[r2][ch]     = bf2f((ushort)(u & 0xffff));
        Ol[r2 + 1][ch] = bf2f((ushort)(u >> 16));
    }
    __syncthreads();   // Ol complete (cross-wave)

    // ---- LN over C=32 (thread = row lane>>2, seg lane&3) ----
    union { ushort us[8]; uint u4[4]; } anp;
    {
        const int r = lane >> 2, seg = lane & 3;
        float v[8];
        #pragma unroll
        for (int e = 0; e < 8; ++e) v[e] = Ol[wrow + r][seg * 8 + e];
        float s = 0.f, ss = 0.f;
        #pragma unroll
        for (int e = 0; e < 8; ++e) { s += v[e]; ss += v[e] * v[e]; }
        s += __shfl_xor(s, 1); ss += __shfl_xor(ss, 1);
        s += __shfl_xor(s, 2); ss += __shfl_xor(ss, 2);
        const float mu  = s * (1.f / 32.f);
        const float var = ss * (1.f / 32.f) - mu * mu;
        const float rs  = rsqrtf(var + 1e-5f);
        #pragma unroll
        for (int e = 0; e < 8; ++e) {
            const int c = seg * 8 + e;
            anp.us[e] = f2bf((v[e] - mu) * rs * onw[c] + onb[c]);
        }
    }
    // ---- An A-frag via shuffle: lane (fr,hi) <- LN thread 4*fr+hi ----
    bf16x8 afo;
    {
        const int src = 4 * fr + hi;
        union { uint u[4]; bf16x8 v; } t;
        #pragma unroll
        for (int m = 0; m < 4; ++m)
            t.u[m] = (uint)__shfl((int)anp.u4[m], src);
        afo = t.v;
    }

    const ushort* glp = gfrag + (size_t)lane * 8;
    const ushort* olp = ofrag + (size_t)lane * 8;

    // ---- two 64-channel halves ----
    #pragma unroll
    for (int h = 0; h < 2; ++h) {
        f32x4 po[4], pg[4];
        #pragma unroll
        for (int nn = 0; nn < 4; ++nn) {
            const int n = h * 4 + nn;
            po[nn] = __builtin_amdgcn_mfma_f32_16x16x32_bf16(
                afo, *(const bf16x8*)(olp + (size_t)n * 512),
                (f32x4){0.f, 0.f, 0.f, 0.f}, 0, 0, 0);
            pg[nn] = (f32x4){0.f, 0.f, 0.f, 0.f};
            #pragma unroll
            for (int kk = 0; kk < 4; ++kk)
                pg[nn] = __builtin_amdgcn_mfma_f32_16x16x32_bf16(
                    afg[kk], *(const bf16x8*)(glp + (size_t)(n * 4 + kk) * 512),
                    pg[nn], 0, 0, 0);
        }
        #pragma unroll
        for (int nn = 0; nn < 4; ++nn) {
            const int ch = (h * 4 + nn) * 16 + fr;
            const float obv = obias[ch], gbv = gb[ch];
            #pragma unroll
            for (int q = 0; q < 4; ++q)
                Res[wave][hi * 4 + q][nn * 16 + fr] =
                    (po[nn][q] + obv) * sigm(pg[nn][q] + gbv);
        }
        #pragma unroll
        for (int i = 0; i < 4; ++i) {
            const int r = i * 4 + hi;
            *(float4*)&out[(rowbase + wrow + r) * ZD + h * 64 + fr * 4] =
                *(const float4*)&Res[wave][r][fr * 4];
        }
    }
}

extern "C" void kernel_launch(void* const* d_in, const int* in_sizes, int n_in,
                              void* d_out, int out_size, void* d_ws, size_t ws_size,
                              hipStream_t stream) {
    (void)in_sizes; (void)n_in; (void)out_size; (void)ws_size;
    const float* z   = (const float*)d_in[0];
    const float* nw  = (const float*)d_in[1];
    const float* nb  = (const float*)d_in[2];
    const float* onw = (const float*)d_in[3];
    const float* onb = (const float*)d_in[4];
    const float* aw  = (const float*)d_in[5];
    const float* ab  = (const float*)d_in[6];
    const float* agw = (const float*)d_in[7];
    const float* agb = (const float*)d_in[8];
    const float* gw  = (const float*)d_in[9];
    const float* gb  = (const float*)d_in[10];
    const float* ow  = (const float*)d_in[11];
    const float* ob  = (const float*)d_in[12];

    char* ws = (char*)d_ws;
    ushort* a_t    = (ushort*)ws;                       // 37,748,736 B
    ushort* znfrag = (ushort*)(ws + 37748736);          // 150,994,944 B
    ushort* obuf16 = (ushort*)(ws + 188743680);         // 37,748,736 B
    ushort* afrag  = (ushort*)(ws + 226492416);         // 16,384 B
    ushort* gfrag  = (ushort*)(ws + 226508800);         // 32,768 B
    ushort* ofrag  = (ushort*)(ws + 226541568);         // 8,192 B

    k0_frags<<<14, 256, 0, stream>>>(aw, agw, gw, ow, afrag, gfrag, ofrag);
    k1_ln_proj<<<LL / 256, 256, 0, stream>>>(z, nw, nb, afrag, ab, agb,
                                             a_t, znfrag);
    k2_einsum<<<dim3(78, 32), 256, 0, stream>>>(a_t, obuf16);
    k3_out<<<LL / 64, 256, 0, stream>>>(obuf16, znfrag, onw, onb, gfrag, ofrag,
                                        ob, gb, (float*)d_out);
}

// Round 10
// 314.618 us; speedup vs baseline: 1.0133x; 1.0133x over previous
//
#include <hip/hip_runtime.h>
#include <math.h>

// TriOut: z[L,L,Z] -> LN -> gated proj to C -> einsum('ilc,jlc->ijc') -> LN(C)
//         -> proj back to Z -> * sigmoid(zn@g_w+g_b)
// L=768, Z=128, C=32.  Output fp32 [L,L,Z].
//
// ws layout (disjoint):
//   a_t   : bf16 [C][L*L]   ( 37,748,736 B) @ 0          a, c-major
//   gate  : bf16 [L*L][Z]   (150,994,944 B) @ 37748736   sigmoid(zn@g_w+g_b)
//   obuf16: bf16 [C][L*L]   ( 37,748,736 B) @ 188743680  einsum result, c-major
//   wfrag : bf16 [12*4][64][8] (49,152 B)   @ 226492416  a/ag/g weights, frag order

#define LDIM 768
#define LL   (768 * 768)
#define ZD   128
#define CD   32

typedef __bf16 bf16x8 __attribute__((ext_vector_type(8)));
typedef float  f32x4  __attribute__((ext_vector_type(4)));

__device__ __forceinline__ ushort f2bf(float f) {
    __bf16 h = (__bf16)f;                      // RNE convert
    return __builtin_bit_cast(ushort, h);
}
__device__ __forceinline__ float bf2f(ushort u) {
    return __builtin_bit_cast(float, ((unsigned)u) << 16);
}
// fast sigmoid: v_exp_f32 + v_rcp_f32 (~1 ulp fp32 -- far below bf16 rounding)
__device__ __forceinline__ float sigm(float x) {
    return __builtin_amdgcn_rcpf(1.0f + __expf(-x));
}

// ---------------------------------------------------------------------------
// k0: pack [a_w ; ag_w ; g_w] -> bf16 wfrag in MFMA B-FRAGMENT ORDER:
//   frag f = n*4+kk, lane l = fr + 16*hi:
//     wfrag[f*64 + l][j] = W[n*16+fr][kk*32 + hi*8 + j],  j=0..7
// ---------------------------------------------------------------------------
__global__ __launch_bounds__(256) void k0_wfrag(
    const float* __restrict__ aw, const float* __restrict__ agw,
    const float* __restrict__ gw, ushort* __restrict__ wfrag)
{
    const int f = blockIdx.x * 256 + threadIdx.x;     // 3072 frags
    if (f >= 12 * 4 * 64) return;
    const int n4 = f >> 6, lane = f & 63;
    const int n = n4 >> 2, kk = n4 & 3;
    const int fr = lane & 15, hi = lane >> 4;
    const int ch = n * 16 + fr;
    const int k0 = kk * 32 + hi * 8;
    const float* src = (ch < 32) ? (aw + ch * ZD)
                     : (ch < 64) ? (agw + (ch - 32) * ZD)
                                 : (gw + (ch - 64) * ZD);
    union { ushort us[8]; uint4 q; } pk;
    #pragma unroll
    for (int j = 0; j < 8; ++j) pk.us[j] = f2bf(src[k0 + j]);
    *(uint4*)&wfrag[(size_t)f * 8] = pk.q;
}

// ---------------------------------------------------------------------------
// k1 v6: 2304 blocks x 4 chunks of 64 rows, channel-split (proven R7 form),
// MINUS the gate LDS-transpose: gate written directly from the epilogue as
// ushort stores (16 fr-lanes = contiguous 32B run; block covers each row's
// full 256B so L2 write-back assembles full lines).  LDS = zn only (17.4 KB),
// 2 barriers/chunk, no bank-conflict-heavy gl writes.
//   wave w owns 3 n-tiles for ALL 64 rows:
//     w0:{0(a0),2(ag0),4(g0)}  w1:{1(a1),3(ag1),5(g1)}  w2:{6,7,8}  w3:{9,10,11}
// ---------------------------------------------------------------------------
__global__ __launch_bounds__(256) void k1_ln_proj(
    const float* __restrict__ z, const float* __restrict__ nw, const float* __restrict__ nb,
    const ushort* __restrict__ wfrag,
    const float* __restrict__ ab, const float* __restrict__ agb, const float* __restrict__ gb,
    ushort* __restrict__ a_t, ushort* __restrict__ gate)
{
    __shared__ ushort zn[64][136];

    const int tid = threadIdx.x;
    const int lane = tid & 63, wave = tid >> 6;
    const int fr = lane & 15, hi = lane >> 4;

    // owned n-tiles
    const int t0 = (wave < 2) ? wave     : 6 + (wave - 2) * 3;
    const int t1 = (wave < 2) ? wave + 2 : t0 + 1;
    const int t2 = (wave < 2) ? wave + 4 : t0 + 2;

    // B-fragments: loaded once, held in registers (12 x 4 VGPR)
    bf16x8 bv0[4], bv1[4], bv2[4];
    {
        const ushort* wl = wfrag + (size_t)lane * 8;
        #pragma unroll
        for (int kk = 0; kk < 4; ++kk) {
            bv0[kk] = *(const bf16x8*)(wl + (size_t)(t0 * 4 + kk) * 512);
            bv1[kk] = *(const bf16x8*)(wl + (size_t)(t1 * 4 + kk) * 512);
            bv2[kk] = *(const bf16x8*)(wl + (size_t)(t2 * 4 + kk) * 512);
        }
    }

    // biases (per-lane scalars, hoisted)
    float abv = 0.f, agbv = 0.f, gbv0 = 0.f, gbv1 = 0.f, gbv2;
    if (wave < 2) {
        abv  = ab[wave * 16 + fr];
        agbv = agb[wave * 16 + fr];
        gbv2 = gb[t2 * 16 - 64 + fr];
    } else {
        gbv0 = gb[t0 * 16 - 64 + fr];
        gbv1 = gb[t1 * 16 - 64 + fr];
        gbv2 = gb[t2 * 16 - 64 + fr];
    }

    const size_t blockrow = (size_t)blockIdx.x * 256;
    const int lr = tid >> 2, seg = tid & 3;     // LN: 4 threads/row

    float4 zreg[8];
    {
        const float4* zp = (const float4*)(z + (blockrow + lr) * ZD + seg * 32);
        #pragma unroll
        for (int q = 0; q < 8; ++q) zreg[q] = zp[q];
    }

    for (int c = 0; c < 4; ++c) {
        __syncthreads();   // zn safe to rewrite (prev chunk fully consumed)

        // ---- LN from prefetched regs -> zn bf16 ----
        {
            float v[32];
            #pragma unroll
            for (int q = 0; q < 8; ++q) {
                v[q * 4 + 0] = zreg[q].x; v[q * 4 + 1] = zreg[q].y;
                v[q * 4 + 2] = zreg[q].z; v[q * 4 + 3] = zreg[q].w;
            }
            float s = 0.f, ss = 0.f;
            #pragma unroll
            for (int e = 0; e < 32; ++e) { s += v[e]; ss += v[e] * v[e]; }
            s += __shfl_xor(s, 1); ss += __shfl_xor(ss, 1);
            s += __shfl_xor(s, 2); ss += __shfl_xor(ss, 2);
            const float mu  = s * (1.f / 128.f);
            const float var = ss * (1.f / 128.f) - mu * mu;
            const float rs  = rsqrtf(var + 1e-5f);
            union { ushort u[32]; uint4 q4[4]; } pk;
            #pragma unroll
            for (int e = 0; e < 32; ++e) {
                const int k = seg * 32 + e;
                pk.u[e] = f2bf((v[e] - mu) * rs * nw[k] + nb[k]);
            }
            #pragma unroll
            for (int q = 0; q < 4; ++q)
                *(uint4*)&zn[lr][seg * 32 + q * 8] = pk.q4[q];
        }

        // ---- prefetch next chunk's z (regs are dead after the pack) ----
        if (c < 3) {
            const float4* zp = (const float4*)(z + (blockrow + (c + 1) * 64 + lr) * ZD + seg * 32);
            #pragma unroll
            for (int q = 0; q < 8; ++q) zreg[q] = zp[q];
        }
        __syncthreads();   // zn ready

        // ---- MFMA: 4 m-tiles x 3 owned n-tiles x 4 k ----
        f32x4 acc0[4], acc1[4], acc2[4];
        #pragma unroll
        for (int m = 0; m < 4; ++m) {
            acc0[m] = (f32x4){0.f, 0.f, 0.f, 0.f};
            acc1[m] = (f32x4){0.f, 0.f, 0.f, 0.f};
            acc2[m] = (f32x4){0.f, 0.f, 0.f, 0.f};
        }
        #pragma unroll
        for (int m = 0; m < 4; ++m) {
            bf16x8 afm[4];
            #pragma unroll
            for (int kk = 0; kk < 4; ++kk)
                afm[kk] = *(const bf16x8*)&zn[m * 16 + fr][kk * 32 + hi * 8];
            #pragma unroll
            for (int kk = 0; kk < 4; ++kk) {
                acc0[m] = __builtin_amdgcn_mfma_f32_16x16x32_bf16(afm[kk], bv0[kk], acc0[m], 0, 0, 0);
                acc1[m] = __builtin_amdgcn_mfma_f32_16x16x32_bf16(afm[kk], bv1[kk], acc1[m], 0, 0, 0);
                acc2[m] = __builtin_amdgcn_mfma_f32_16x16x32_bf16(afm[kk], bv2[kk], acc2[m], 0, 0, 0);
            }
        }

        // ---- epilogue: direct global stores, no LDS, no 3rd barrier ----
        const size_t rb = blockrow + (size_t)c * 64;
        if (wave < 2) {
            // a = (a_lin + ab) * sigm(ag_lin + agb) -> a_t c-major
            const int ch = wave * 16 + fr;
            #pragma unroll
            for (int m = 0; m < 4; ++m) {
                union { ushort u[4]; uint2 d; } pk;
                #pragma unroll
                for (int q = 0; q < 4; ++q)
                    pk.u[q] = f2bf((acc0[m][q] + abv) * sigm(acc1[m][q] + agbv));
                *(uint2*)&a_t[(size_t)ch * LL + rb + m * 16 + hi * 4] = pk.d;
            }
            // gate tile t2 -> direct scattered stores
            const int gch = t2 * 16 - 64 + fr;
            #pragma unroll
            for (int m = 0; m < 4; ++m)
                #pragma unroll
                for (int q = 0; q < 4; ++q)
                    gate[(rb + m * 16 + hi * 4 + q) * ZD + gch] =
                        f2bf(sigm(acc2[m][q] + gbv2));
        } else {
            const int g0 = t0 * 16 - 64 + fr;
            const int g1 = t1 * 16 - 64 + fr;
            const int g2 = t2 * 16 - 64 + fr;
            #pragma unroll
            for (int m = 0; m < 4; ++m)
                #pragma unroll
                for (int q = 0; q < 4; ++q) {
                    const size_t row = rb + m * 16 + hi * 4 + q;
                    gate[row * ZD + g0] = f2bf(sigm(acc0[m][q] + gbv0));
                    gate[row * ZD + g1] = f2bf(sigm(acc1[m][q] + gbv1));
                    gate[row * ZD + g2] = f2bf(sigm(acc2[m][q] + gbv2));
                }
        }
    }
}

// ---------------------------------------------------------------------------
// k2: 32 batched SYMMETRIC GEMMs  O_c = M_c * M_c^T, upper-triangular tiles
// only (78 pairs), mirror-write for off-diagonal.  Output bf16 obuf16.
// Staging via global_load_lds (linear dest = tid*16B).
// ---------------------------------------------------------------------------
__global__ __launch_bounds__(256) void k2_einsum(
    const ushort* __restrict__ a_t, ushort* __restrict__ obuf16)
{
    __shared__ ushort As[2][64][32];
    __shared__ ushort Bs[2][64][32];

    const int tid = threadIdx.x;
    const int c = blockIdx.y;
    int p = blockIdx.x, bi = 0;
    while (p >= 12 - bi) { p -= 12 - bi; ++bi; }
    const int bj = bi + p;
    const int i0 = bi * 64, j0 = bj * 64;
    const ushort* base = a_t + (size_t)c * LL;

    const int srow = tid >> 2, scol = (tid & 3) * 8;
    const ushort* gA = base + (size_t)(i0 + srow) * LDIM + scol;
    const ushort* gB = base + (size_t)(j0 + srow) * LDIM + scol;

    const int wave = tid >> 6, lane = tid & 63;
    const int wi = (wave >> 1) * 32, wj = (wave & 1) * 32;
    const int fr = lane & 15, k8 = (lane >> 4) * 8;

    f32x4 acc[2][2];
    #pragma unroll
    for (int m = 0; m < 2; ++m)
        #pragma unroll
        for (int n = 0; n < 2; ++n)
            acc[m][n] = (f32x4){0.f, 0.f, 0.f, 0.f};

    auto stage = [&](int b, int kc) {
        __builtin_amdgcn_global_load_lds(
            (const uint*)(gA + kc * 32), (uint*)&As[b][srow][scol], 16, 0, 0);
        __builtin_amdgcn_global_load_lds(
            (const uint*)(gB + kc * 32), (uint*)&Bs[b][srow][scol], 16, 0, 0);
    };

    stage(0, 0);
    __syncthreads();
    for (int kc = 0; kc < 24; ++kc) {
        const int cur = kc & 1;
        if (kc + 1 < 24) stage(cur ^ 1, kc + 1);

        bf16x8 av[2], bv[2];
        #pragma unroll
        for (int m = 0; m < 2; ++m)
            av[m] = *(const bf16x8*)&As[cur][wi + m * 16 + fr][k8];
        #pragma unroll
        for (int n = 0; n < 2; ++n)
            bv[n] = *(const bf16x8*)&Bs[cur][wj + n * 16 + fr][k8];

        #pragma unroll
        for (int m = 0; m < 2; ++m)
            #pragma unroll
            for (int n = 0; n < 2; ++n)
                acc[m][n] = __builtin_amdgcn_mfma_f32_16x16x32_bf16(
                    av[m], bv[n], acc[m][n], 0, 0, 0);
        __syncthreads();
    }

    ushort* ob = obuf16 + (size_t)c * LL;
    #pragma unroll
    for (int m = 0; m < 2; ++m)
        #pragma unroll
        for (int n = 0; n < 2; ++n) {
            #pragma unroll
            for (int q = 0; q < 4; ++q) {
                const int row = i0 + wi + m * 16 + (lane >> 4) * 4 + q;
                const int col = j0 + wj + n * 16 + fr;
                ob[(size_t)row * LDIM + col] = f2bf(acc[m][n][q]);
            }
            if (bi != bj) {
                const int mrow = j0 + wj + n * 16 + fr;
                const int mcol = i0 + wi + m * 16 + (lane >> 4) * 4;
                union { ushort u[4]; uint2 d; } pk;
                #pragma unroll
                for (int q = 0; q < 4; ++q) pk.u[q] = f2bf(acc[m][n][q]);
                *(uint2*)&ob[(size_t)mrow * LDIM + mcol] = pk.d;
            }
        }
}

// ---------------------------------------------------------------------------
// k3 (R7 v1 + bf16 gather): per 64 flat rows:
//   gather obuf16 (c-major) -> LDS, LN over C=32 (affine) -> bf16 An[64][36],
//   o_w staged bf16 Bw[128][36]; wave w: rows w*16..+15 x 128 out = 8 MFMA;
//   +o_b -> fp32 Res (aliased over gather buf); Res * gate -> out, coalesced.
// ---------------------------------------------------------------------------
__global__ __launch_bounds__(256) void k3_out(
    const ushort* __restrict__ obuf16,
    const float* __restrict__ onw, const float* __restrict__ onb,
    const float* __restrict__ ow,  const float* __restrict__ obias,
    const ushort* __restrict__ gate, float* __restrict__ out)
{
    __shared__ union { float Ol[64][40]; float Res[64][132]; } u;
    __shared__ ushort An[64][36];
    __shared__ ushort Bw[128][36];

    const int tid = threadIdx.x;
    const int lane = tid & 63, wave = tid >> 6;
    const size_t rowbase = (size_t)blockIdx.x * 64;

    // ---- gather obuf16 (c-major bf16): wave handles 8 channels, 2 rows/uint ----
    #pragma unroll
    for (int cc = 0; cc < 4; ++cc) {
        const int ch = wave * 8 + cc * 2 + (lane >> 5);
        const int r2 = (lane & 31) * 2;
        const uint uu = *(const uint*)&obuf16[(size_t)ch * LL + rowbase + r2];
        u.Ol[r2][ch]     = bf2f((ushort)(uu & 0xffff));
        u.Ol[r2 + 1][ch] = bf2f((ushort)(uu >> 16));
    }
    // ---- stage o_w -> bf16 Bw: thread t -> row t>>1, 16-ch half t&1 ----
    {
        const int r = tid >> 1, h = tid & 1;
        const float* src = ow + r * CD + h * 16;
        union { ushort us[16]; uint4 q[2]; } pk;
        #pragma unroll
        for (int e = 0; e < 16; ++e) pk.us[e] = f2bf(src[e]);
        *(uint4*)&Bw[r][h * 16]     = pk.q[0];
        *(uint4*)&Bw[r][h * 16 + 8] = pk.q[1];
    }
    __syncthreads();

    // ---- LN over C=32: 4 threads/row, 8 ch each, affine -> bf16 An ----
    {
        const int r = tid >> 2, seg = tid & 3;
        float v[8];
        #pragma unroll
        for (int e = 0; e < 8; ++e) v[e] = u.Ol[r][seg * 8 + e];
        float s = 0.f, ss = 0.f;
        #pragma unroll
        for (int e = 0; e < 8; ++e) { s += v[e]; ss += v[e] * v[e]; }
        s += __shfl_xor(s, 1); ss += __shfl_xor(ss, 1);
        s += __shfl_xor(s, 2); ss += __shfl_xor(ss, 2);
        const float mu  = s * (1.f / 32.f);
        const float var = ss * (1.f / 32.f) - mu * mu;
        const float rs  = rsqrtf(var + 1e-5f);
        union { ushort us[8]; uint4 q; } pk;
        #pragma unroll
        for (int e = 0; e < 8; ++e) {
            const int c = seg * 8 + e;
            pk.us[e] = f2bf((v[e] - mu) * rs * onw[c] + onb[c]);
        }
        *(uint4*)&An[r][seg * 8] = pk.q;
    }
    __syncthreads();   // An/Bw ready; Ol dead beyond this point

    // ---- MFMA: wave w -> rows w*16..+15, 128 outputs, single k-step ----
    const int fr = lane & 15, hi = lane >> 4;
    const int wrow = wave * 16;

    const bf16x8 af = *(const bf16x8*)&An[wrow + fr][hi * 8];
    f32x4 acc[8];
    #pragma unroll
    for (int n = 0; n < 8; ++n) {
        const bf16x8 bv = *(const bf16x8*)&Bw[n * 16 + fr][hi * 8];
        acc[n] = __builtin_amdgcn_mfma_f32_16x16x32_bf16(
            af, bv, (f32x4){0.f, 0.f, 0.f, 0.f}, 0, 0, 0);
    }

    // ---- +bias -> Res (aliases dead Ol) ----
    #pragma unroll
    for (int n = 0; n < 8; ++n) {
        const int ch = n * 16 + fr;
        const float obv = obias[ch];
        #pragma unroll
        for (int q = 0; q < 4; ++q)
            u.Res[wrow + hi * 4 + q][ch] = acc[n][q] + obv;
    }
    __syncthreads();

    // ---- Res * gate -> out, coalesced ----
    #pragma unroll
    for (int it = 0; it < 8; ++it) {
        const int idx = it * 256 + tid;          // 2048 float4 chunks
        const int r = idx >> 5, cq = (idx & 31) * 4;
        float4 v4 = *(const float4*)&u.Res[r][cq];
        union { uint2 d; ushort us[4]; } g;
        g.d = *(const uint2*)&gate[(rowbase + r) * ZD + cq];
        v4.x *= bf2f(g.us[0]); v4.y *= bf2f(g.us[1]);
        v4.z *= bf2f(g.us[2]); v4.w *= bf2f(g.us[3]);
        *(float4*)&out[(rowbase + r) * ZD + cq] = v4;
    }
}

extern "C" void kernel_launch(void* const* d_in, const int* in_sizes, int n_in,
                              void* d_out, int out_size, void* d_ws, size_t ws_size,
                              hipStream_t stream) {
    (void)in_sizes; (void)n_in; (void)out_size; (void)ws_size;
    const float* z   = (const float*)d_in[0];
    const float* nw  = (const float*)d_in[1];
    const float* nb  = (const float*)d_in[2];
    const float* onw = (const float*)d_in[3];
    const float* onb = (const float*)d_in[4];
    const float* aw  = (const float*)d_in[5];
    const float* ab  = (const float*)d_in[6];
    const float* agw = (const float*)d_in[7];
    const float* agb = (const float*)d_in[8];
    const float* gw  = (const float*)d_in[9];
    const float* gb  = (const float*)d_in[10];
    const float* ow  = (const float*)d_in[11];
    const float* ob  = (const float*)d_in[12];

    char* ws = (char*)d_ws;
    ushort* a_t    = (ushort*)ws;                       // 37,748,736 B
    ushort* gate   = (ushort*)(ws + 37748736);          // 150,994,944 B
    ushort* obuf16 = (ushort*)(ws + 188743680);         // 37,748,736 B
    ushort* wfrag  = (ushort*)(ws + 226492416);         // 49,152 B

    k0_wfrag<<<12, 256, 0, stream>>>(aw, agw, gw, wfrag);
    k1_ln_proj<<<LL / 256, 256, 0, stream>>>(z, nw, nb, wfrag, ab, agb, gb,
                                             a_t, gate);
    k2_einsum<<<dim3(78, 32), 256, 0, stream>>>(a_t, obuf16);
    k3_out<<<LL / 64, 256, 0, stream>>>(obuf16, onw, onb, ow, ob, gate,
                                        (float*)d_out);
}

// Round 11
// 279.969 us; speedup vs baseline: 1.1387x; 1.1238x over previous
//
#include <hip/hip_runtime.h>
#include <math.h>

// TriOut: z[L,L,Z] -> LN -> gated proj to C -> einsum('ilc,jlc->ijc') -> LN(C)
//         -> proj back to Z -> * sigmoid(zn@g_w+g_b)
// L=768, Z=128, C=32.  Output fp32 [L,L,Z].
//
// ws layout (disjoint):
//   a_t   : bf16 [C][L*L]   ( 37,748,736 B) @ 0          a, c-major
//   gate  : bf16 [L*L][Z]   (150,994,944 B) @ 37748736   sigmoid(zn@g_w+g_b)
//   obuf16: bf16 [C][L*L]   ( 37,748,736 B) @ 188743680  einsum result, c-major
//   wfrag : bf16 [12*4][64][8] (49,152 B)   @ 226492416  a/ag/g weights, frag order

#define LDIM 768
#define LL   (768 * 768)
#define ZD   128
#define CD   32

typedef __bf16 bf16x8 __attribute__((ext_vector_type(8)));
typedef float  f32x4  __attribute__((ext_vector_type(4)));

__device__ __forceinline__ ushort f2bf(float f) {
    __bf16 h = (__bf16)f;                      // RNE convert
    return __builtin_bit_cast(ushort, h);
}
__device__ __forceinline__ float bf2f(ushort u) {
    return __builtin_bit_cast(float, ((unsigned)u) << 16);
}
// fast sigmoid: v_exp_f32 + v_rcp_f32 (~1 ulp fp32 -- far below bf16 rounding)
__device__ __forceinline__ float sigm(float x) {
    return __builtin_amdgcn_rcpf(1.0f + __expf(-x));
}

// ---------------------------------------------------------------------------
// k0: pack [a_w ; ag_w ; g_w] -> bf16 wfrag in MFMA B-FRAGMENT ORDER:
//   frag f = n*4+kk, lane l = fr + 16*hi:
//     wfrag[f*64 + l][j] = W[n*16+fr][kk*32 + hi*8 + j],  j=0..7
// ---------------------------------------------------------------------------
__global__ __launch_bounds__(256) void k0_wfrag(
    const float* __restrict__ aw, const float* __restrict__ agw,
    const float* __restrict__ gw, ushort* __restrict__ wfrag)
{
    const int f = blockIdx.x * 256 + threadIdx.x;     // 3072 frags
    if (f >= 12 * 4 * 64) return;
    const int n4 = f >> 6, lane = f & 63;
    const int n = n4 >> 2, kk = n4 & 3;
    const int fr = lane & 15, hi = lane >> 4;
    const int ch = n * 16 + fr;
    const int k0 = kk * 32 + hi * 8;
    const float* src = (ch < 32) ? (aw + ch * ZD)
                     : (ch < 64) ? (agw + (ch - 32) * ZD)
                                 : (gw + (ch - 64) * ZD);
    union { ushort us[8]; uint4 q; } pk;
    #pragma unroll
    for (int j = 0; j < 8; ++j) pk.us[j] = f2bf(src[k0 + j]);
    *(uint4*)&wfrag[(size_t)f * 8] = pk.q;
}

// ---------------------------------------------------------------------------
// k1 v3 (R7 measured-best form, reverted verbatim):
// 2304 blocks x 4 chunks of 64 rows.
//   - channel-split: wave w owns 3 n-tiles for ALL 64 rows:
//       w0:{0(a0),2(ag0),4(g0)}  w1:{1(a1),3(ag1),5(g1)}  w2:{6,7,8}  w3:{9,10,11}
//     -> 12 B-frags (48 VGPR) loaded ONCE per block, zero loads in the loop.
//   - z for chunk c+1 prefetched into regs while chunk c computes.
//   - gate epilogue via LDS transpose + coalesced uint4 copy-out (16B stores;
//     direct scattered ushort stores measured WORSE: L2 request-rate bound, R10).
//   - LDS: zn[64][136] + gl[64][136] = 34.8 KB; 3 barriers/chunk.
// ---------------------------------------------------------------------------
__global__ __launch_bounds__(256) void k1_ln_proj(
    const float* __restrict__ z, const float* __restrict__ nw, const float* __restrict__ nb,
    const ushort* __restrict__ wfrag,
    const float* __restrict__ ab, const float* __restrict__ agb, const float* __restrict__ gb,
    ushort* __restrict__ a_t, ushort* __restrict__ gate)
{
    __shared__ ushort zn[64][136];
    __shared__ ushort gl[64][136];

    const int tid = threadIdx.x;
    const int lane = tid & 63, wave = tid >> 6;
    const int fr = lane & 15, hi = lane >> 4;

    // owned n-tiles
    const int t0 = (wave < 2) ? wave     : 6 + (wave - 2) * 3;
    const int t1 = (wave < 2) ? wave + 2 : t0 + 1;
    const int t2 = (wave < 2) ? wave + 4 : t0 + 2;

    // B-fragments: loaded once, held in registers (12 x 4 VGPR)
    bf16x8 bv0[4], bv1[4], bv2[4];
    {
        const ushort* wl = wfrag + (size_t)lane * 8;
        #pragma unroll
        for (int kk = 0; kk < 4; ++kk) {
            bv0[kk] = *(const bf16x8*)(wl + (size_t)(t0 * 4 + kk) * 512);
            bv1[kk] = *(const bf16x8*)(wl + (size_t)(t1 * 4 + kk) * 512);
            bv2[kk] = *(const bf16x8*)(wl + (size_t)(t2 * 4 + kk) * 512);
        }
    }

    // biases (per-lane scalars, hoisted)
    float abv = 0.f, agbv = 0.f, gbv0 = 0.f, gbv1 = 0.f, gbv2;
    if (wave < 2) {
        abv  = ab[wave * 16 + fr];
        agbv = agb[wave * 16 + fr];
        gbv2 = gb[t2 * 16 - 64 + fr];
    } else {
        gbv0 = gb[t0 * 16 - 64 + fr];
        gbv1 = gb[t1 * 16 - 64 + fr];
        gbv2 = gb[t2 * 16 - 64 + fr];
    }

    const size_t blockrow = (size_t)blockIdx.x * 256;
    const int lr = tid >> 2, seg = tid & 3;     // LN: 4 threads/row

    float4 zreg[8];
    {
        const float4* zp = (const float4*)(z + (blockrow + lr) * ZD + seg * 32);
        #pragma unroll
        for (int q = 0; q < 8; ++q) zreg[q] = zp[q];
    }

    for (int c = 0; c < 4; ++c) {
        __syncthreads();   // zn/gl safe to rewrite (prev chunk fully consumed)

        // ---- LN from prefetched regs -> zn bf16 ----
        {
            float v[32];
            #pragma unroll
            for (int q = 0; q < 8; ++q) {
                v[q * 4 + 0] = zreg[q].x; v[q * 4 + 1] = zreg[q].y;
                v[q * 4 + 2] = zreg[q].z; v[q * 4 + 3] = zreg[q].w;
            }
            float s = 0.f, ss = 0.f;
            #pragma unroll
            for (int e = 0; e < 32; ++e) { s += v[e]; ss += v[e] * v[e]; }
            s += __shfl_xor(s, 1); ss += __shfl_xor(ss, 1);
            s += __shfl_xor(s, 2); ss += __shfl_xor(ss, 2);
            const float mu  = s * (1.f / 128.f);
            const float var = ss * (1.f / 128.f) - mu * mu;
            const float rs  = rsqrtf(var + 1e-5f);
            union { ushort u[32]; uint4 q4[4]; } pk;
            #pragma unroll
            for (int e = 0; e < 32; ++e) {
                const int k = seg * 32 + e;
                pk.u[e] = f2bf((v[e] - mu) * rs * nw[k] + nb[k]);
            }
            #pragma unroll
            for (int q = 0; q < 4; ++q)
                *(uint4*)&zn[lr][seg * 32 + q * 8] = pk.q4[q];
        }

        // ---- prefetch next chunk's z (regs are dead after the pack) ----
        if (c < 3) {
            const float4* zp = (const float4*)(z + (blockrow + (c + 1) * 64 + lr) * ZD + seg * 32);
            #pragma unroll
            for (int q = 0; q < 8; ++q) zreg[q] = zp[q];
        }
        __syncthreads();   // zn ready

        // ---- MFMA: 4 m-tiles x 3 owned n-tiles x 4 k ----
        f32x4 acc0[4], acc1[4], acc2[4];
        #pragma unroll
        for (int m = 0; m < 4; ++m) {
            acc0[m] = (f32x4){0.f, 0.f, 0.f, 0.f};
            acc1[m] = (f32x4){0.f, 0.f, 0.f, 0.f};
            acc2[m] = (f32x4){0.f, 0.f, 0.f, 0.f};
        }
        #pragma unroll
        for (int m = 0; m < 4; ++m) {
            bf16x8 afm[4];
            #pragma unroll
            for (int kk = 0; kk < 4; ++kk)
                afm[kk] = *(const bf16x8*)&zn[m * 16 + fr][kk * 32 + hi * 8];
            #pragma unroll
            for (int kk = 0; kk < 4; ++kk) {
                acc0[m] = __builtin_amdgcn_mfma_f32_16x16x32_bf16(afm[kk], bv0[kk], acc0[m], 0, 0, 0);
                acc1[m] = __builtin_amdgcn_mfma_f32_16x16x32_bf16(afm[kk], bv1[kk], acc1[m], 0, 0, 0);
                acc2[m] = __builtin_amdgcn_mfma_f32_16x16x32_bf16(afm[kk], bv2[kk], acc2[m], 0, 0, 0);
            }
        }

        // ---- epilogue ----
        const size_t rb = blockrow + (size_t)c * 64;
        if (wave < 2) {
            // a = (a_lin + ab) * sigm(ag_lin + agb) -> a_t c-major
            const int ch = wave * 16 + fr;
            #pragma unroll
            for (int m = 0; m < 4; ++m) {
                union { ushort u[4]; uint2 d; } pk;
                #pragma unroll
                for (int q = 0; q < 4; ++q)
                    pk.u[q] = f2bf((acc0[m][q] + abv) * sigm(acc1[m][q] + agbv));
                *(uint2*)&a_t[(size_t)ch * LL + rb + m * 16 + hi * 4] = pk.d;
            }
            // gate tile t2 -> gl transpose
            const int gch = t2 * 16 - 64 + fr;
            #pragma unroll
            for (int m = 0; m < 4; ++m)
                #pragma unroll
                for (int q = 0; q < 4; ++q)
                    gl[m * 16 + hi * 4 + q][gch] = f2bf(sigm(acc2[m][q] + gbv2));
        } else {
            const int g0 = t0 * 16 - 64 + fr;
            const int g1 = t1 * 16 - 64 + fr;
            const int g2 = t2 * 16 - 64 + fr;
            #pragma unroll
            for (int m = 0; m < 4; ++m)
                #pragma unroll
                for (int q = 0; q < 4; ++q) {
                    const int row = m * 16 + hi * 4 + q;
                    gl[row][g0] = f2bf(sigm(acc0[m][q] + gbv0));
                    gl[row][g1] = f2bf(sigm(acc1[m][q] + gbv1));
                    gl[row][g2] = f2bf(sigm(acc2[m][q] + gbv2));
                }
        }
        __syncthreads();   // gl complete

        // ---- coalesced gate copy-out ----
        #pragma unroll
        for (int it = 0; it < 4; ++it) {
            const int idx = it * 256 + tid;    // 1024 uint4 chunks
            const int r = idx >> 4, cq = idx & 15;
            *(uint4*)&gate[(rb + r) * ZD + cq * 8] = *(const uint4*)&gl[r][cq * 8];
        }
    }
}

// ---------------------------------------------------------------------------
// k2: 32 batched SYMMETRIC GEMMs  O_c = M_c * M_c^T, upper-triangular tiles
// only (78 pairs), mirror-write for off-diagonal.  Output bf16 obuf16.
// Staging via global_load_lds (linear dest = tid*16B).
// ---------------------------------------------------------------------------
__global__ __launch_bounds__(256) void k2_einsum(
    const ushort* __restrict__ a_t, ushort* __restrict__ obuf16)
{
    __shared__ ushort As[2][64][32];
    __shared__ ushort Bs[2][64][32];

    const int tid = threadIdx.x;
    const int c = blockIdx.y;
    int p = blockIdx.x, bi = 0;
    while (p >= 12 - bi) { p -= 12 - bi; ++bi; }
    const int bj = bi + p;
    const int i0 = bi * 64, j0 = bj * 64;
    const ushort* base = a_t + (size_t)c * LL;

    const int srow = tid >> 2, scol = (tid & 3) * 8;
    const ushort* gA = base + (size_t)(i0 + srow) * LDIM + scol;
    const ushort* gB = base + (size_t)(j0 + srow) * LDIM + scol;

    const int wave = tid >> 6, lane = tid & 63;
    const int wi = (wave >> 1) * 32, wj = (wave & 1) * 32;
    const int fr = lane & 15, k8 = (lane >> 4) * 8;

    f32x4 acc[2][2];
    #pragma unroll
    for (int m = 0; m < 2; ++m)
        #pragma unroll
        for (int n = 0; n < 2; ++n)
            acc[m][n] = (f32x4){0.f, 0.f, 0.f, 0.f};

    auto stage = [&](int b, int kc) {
        __builtin_amdgcn_global_load_lds(
            (const uint*)(gA + kc * 32), (uint*)&As[b][srow][scol], 16, 0, 0);
        __builtin_amdgcn_global_load_lds(
            (const uint*)(gB + kc * 32), (uint*)&Bs[b][srow][scol], 16, 0, 0);
    };

    stage(0, 0);
    __syncthreads();
    for (int kc = 0; kc < 24; ++kc) {
        const int cur = kc & 1;
        if (kc + 1 < 24) stage(cur ^ 1, kc + 1);

        bf16x8 av[2], bv[2];
        #pragma unroll
        for (int m = 0; m < 2; ++m)
            av[m] = *(const bf16x8*)&As[cur][wi + m * 16 + fr][k8];
        #pragma unroll
        for (int n = 0; n < 2; ++n)
            bv[n] = *(const bf16x8*)&Bs[cur][wj + n * 16 + fr][k8];

        #pragma unroll
        for (int m = 0; m < 2; ++m)
            #pragma unroll
            for (int n = 0; n < 2; ++n)
                acc[m][n] = __builtin_amdgcn_mfma_f32_16x16x32_bf16(
                    av[m], bv[n], acc[m][n], 0, 0, 0);
        __syncthreads();
    }

    ushort* ob = obuf16 + (size_t)c * LL;
    #pragma unroll
    for (int m = 0; m < 2; ++m)
        #pragma unroll
        for (int n = 0; n < 2; ++n) {
            #pragma unroll
            for (int q = 0; q < 4; ++q) {
                const int row = i0 + wi + m * 16 + (lane >> 4) * 4 + q;
                const int col = j0 + wj + n * 16 + fr;
                ob[(size_t)row * LDIM + col] = f2bf(acc[m][n][q]);
            }
            if (bi != bj) {
                const int mrow = j0 + wj + n * 16 + fr;
                const int mcol = i0 + wi + m * 16 + (lane >> 4) * 4;
                union { ushort u[4]; uint2 d; } pk;
                #pragma unroll
                for (int q = 0; q < 4; ++q) pk.u[q] = f2bf(acc[m][n][q]);
                *(uint2*)&ob[(size_t)mrow * LDIM + mcol] = pk.d;
            }
        }
}

// ---------------------------------------------------------------------------
// k3 (R7 v1 + bf16 gather): per 64 flat rows:
//   gather obuf16 (c-major) -> LDS, LN over C=32 (affine) -> bf16 An[64][36],
//   o_w staged bf16 Bw[128][36]; wave w: rows w*16..+15 x 128 out = 8 MFMA;
//   +o_b -> fp32 Res (aliased over gather buf); Res * gate -> out, coalesced.
// ---------------------------------------------------------------------------
__global__ __launch_bounds__(256) void k3_out(
    const ushort* __restrict__ obuf16,
    const float* __restrict__ onw, const float* __restrict__ onb,
    const float* __restrict__ ow,  const float* __restrict__ obias,
    const ushort* __restrict__ gate, float* __restrict__ out)
{
    __shared__ union { float Ol[64][40]; float Res[64][132]; } u;
    __shared__ ushort An[64][36];
    __shared__ ushort Bw[128][36];

    const int tid = threadIdx.x;
    const int lane = tid & 63, wave = tid >> 6;
    const size_t rowbase = (size_t)blockIdx.x * 64;

    // ---- gather obuf16 (c-major bf16): wave handles 8 channels, 2 rows/uint ----
    #pragma unroll
    for (int cc = 0; cc < 4; ++cc) {
        const int ch = wave * 8 + cc * 2 + (lane >> 5);
        const int r2 = (lane & 31) * 2;
        const uint uu = *(const uint*)&obuf16[(size_t)ch * LL + rowbase + r2];
        u.Ol[r2][ch]     = bf2f((ushort)(uu & 0xffff));
        u.Ol[r2 + 1][ch] = bf2f((ushort)(uu >> 16));
    }
    // ---- stage o_w -> bf16 Bw: thread t -> row t>>1, 16-ch half t&1 ----
    {
        const int r = tid >> 1, h = tid & 1;
        const float* src = ow + r * CD + h * 16;
        union { ushort us[16]; uint4 q[2]; } pk;
        #pragma unroll
        for (int e = 0; e < 16; ++e) pk.us[e] = f2bf(src[e]);
        *(uint4*)&Bw[r][h * 16]     = pk.q[0];
        *(uint4*)&Bw[r][h * 16 + 8] = pk.q[1];
    }
    __syncthreads();

    // ---- LN over C=32: 4 threads/row, 8 ch each, affine -> bf16 An ----
    {
        const int r = tid >> 2, seg = tid & 3;
        float v[8];
        #pragma unroll
        for (int e = 0; e < 8; ++e) v[e] = u.Ol[r][seg * 8 + e];
        float s = 0.f, ss = 0.f;
        #pragma unroll
        for (int e = 0; e < 8; ++e) { s += v[e]; ss += v[e] * v[e]; }
        s += __shfl_xor(s, 1); ss += __shfl_xor(ss, 1);
        s += __shfl_xor(s, 2); ss += __shfl_xor(ss, 2);
        const float mu  = s * (1.f / 32.f);
        const float var = ss * (1.f / 32.f) - mu * mu;
        const float rs  = rsqrtf(var + 1e-5f);
        union { ushort us[8]; uint4 q; } pk;
        #pragma unroll
        for (int e = 0; e < 8; ++e) {
            const int c = seg * 8 + e;
            pk.us[e] = f2bf((v[e] - mu) * rs * onw[c] + onb[c]);
        }
        *(uint4*)&An[r][seg * 8] = pk.q;
    }
    __syncthreads();   // An/Bw ready; Ol dead beyond this point

    // ---- MFMA: wave w -> rows w*16..+15, 128 outputs, single k-step ----
    const int fr = lane & 15, hi = lane >> 4;
    const int wrow = wave * 16;

    const bf16x8 af = *(const bf16x8*)&An[wrow + fr][hi * 8];
    f32x4 acc[8];
    #pragma unroll
    for (int n = 0; n < 8; ++n) {
        const bf16x8 bv = *(const bf16x8*)&Bw[n * 16 + fr][hi * 8];
        acc[n] = __builtin_amdgcn_mfma_f32_16x16x32_bf16(
            af, bv, (f32x4){0.f, 0.f, 0.f, 0.f}, 0, 0, 0);
    }

    // ---- +bias -> Res (aliases dead Ol) ----
    #pragma unroll
    for (int n = 0; n < 8; ++n) {
        const int ch = n * 16 + fr;
        const float obv = obias[ch];
        #pragma unroll
        for (int q = 0; q < 4; ++q)
            u.Res[wrow + hi * 4 + q][ch] = acc[n][q] + obv;
    }
    __syncthreads();

    // ---- Res * gate -> out, coalesced ----
    #pragma unroll
    for (int it = 0; it < 8; ++it) {
        const int idx = it * 256 + tid;          // 2048 float4 chunks
        const int r = idx >> 5, cq = (idx & 31) * 4;
        float4 v4 = *(const float4*)&u.Res[r][cq];
        union { uint2 d; ushort us[4]; } g;
        g.d = *(const uint2*)&gate[(rowbase + r) * ZD + cq];
        v4.x *= bf2f(g.us[0]); v4.y *= bf2f(g.us[1]);
        v4.z *= bf2f(g.us[2]); v4.w *= bf2f(g.us[3]);
        *(float4*)&out[(rowbase + r) * ZD + cq] = v4;
    }
}

extern "C" void kernel_launch(void* const* d_in, const int* in_sizes, int n_in,
                              void* d_out, int out_size, void* d_ws, size_t ws_size,
                              hipStream_t stream) {
    (void)in_sizes; (void)n_in; (void)out_size; (void)ws_size;
    const float* z   = (const float*)d_in[0];
    const float* nw  = (const float*)d_in[1];
    const float* nb  = (const float*)d_in[2];
    const float* onw = (const float*)d_in[3];
    const float* onb = (const float*)d_in[4];
    const float* aw  = (const float*)d_in[5];
    const float* ab  = (const float*)d_in[6];
    const float* agw = (const float*)d_in[7];
    const float* agb = (const float*)d_in[8];
    const float* gw  = (const float*)d_in[9];
    const float* gb  = (const float*)d_in[10];
    const float* ow  = (const float*)d_in[11];
    const float* ob  = (const float*)d_in[12];

    char* ws = (char*)d_ws;
    ushort* a_t    = (ushort*)ws;                       // 37,748,736 B
    ushort* gate   = (ushort*)(ws + 37748736);          // 150,994,944 B
    ushort* obuf16 = (ushort*)(ws + 188743680);         // 37,748,736 B
    ushort* wfrag  = (ushort*)(ws + 226492416);         // 49,152 B

    k0_wfrag<<<12, 256, 0, stream>>>(aw, agw, gw, wfrag);
    k1_ln_proj<<<LL / 256, 256, 0, stream>>>(z, nw, nb, wfrag, ab, agb, gb,
                                             a_t, gate);
    k2_einsum<<<dim3(78, 32), 256, 0, stream>>>(a_t, obuf16);
    k3_out<<<LL / 64, 256, 0, stream>>>(obuf16, onw, onb, ow, ob, gate,
                                        (float*)d_out);
}